// Round 2
// baseline (1243.795 us; speedup 1.0000x reference)
//
#include <hip/hip_runtime.h>
#include <hip/hip_bf16.h>
#include <math.h>

#define BB 4
#define HH 56
#define WW 56
#define DM 96
#define DI 192
#define NS 16
#define RK 6
#define KG 4
#define LL (HH*WW)          // 3136
#define NPIX (BB*LL)        // 12544
#define SCH 16              // scan LDS chunk (L-steps)
#define CL 8                // xproj pixels per block

// pixel index (row-major) feeding/receiving scan position l of direction k
// k=0: identity, k=1: transpose(HW), k=2: flip(identity), k=3: flip(transpose)
static __device__ __forceinline__ int qmap(int k, int l){
    int m = (k & 2) ? (LL - 1 - l) : l;
    if (k & 1) { int w = m / HH; int h = m % HH; return h * WW + w; }
    return m;
}

static __device__ __forceinline__ float silu(float x){ return x / (1.f + __expf(-x)); }

// ---------------- Stage 1: in_proj (384x96 matvec per pixel), 4 px/block ----
__global__ __launch_bounds__(384) void k_inproj(const float* __restrict__ x,
        const float* __restrict__ Win,
        float* __restrict__ conv_in, float* __restrict__ z_silu)
{
    __shared__ float sx[4*DM];
    int pb  = blockIdx.x * 4;           // absolute pixel base (b*LL+p flattened)
    int tid = threadIdx.x;
    sx[tid] = x[(size_t)pb*DM + tid];
    __syncthreads();
    float a0=0.f, a1=0.f, a2=0.f, a3=0.f;
    const float* wr = Win + (size_t)tid*DM;
    #pragma unroll 4
    for (int i = 0; i < DM; ++i){
        float w = wr[i];
        a0 = fmaf(sx[i],        w, a0);
        a1 = fmaf(sx[DM+i],     w, a1);
        a2 = fmaf(sx[2*DM+i],   w, a2);
        a3 = fmaf(sx[3*DM+i],   w, a3);
    }
    if (tid < DI){
        conv_in[(size_t)(pb+0)*DI + tid] = a0;
        conv_in[(size_t)(pb+1)*DI + tid] = a1;
        conv_in[(size_t)(pb+2)*DI + tid] = a2;
        conv_in[(size_t)(pb+3)*DI + tid] = a3;
    } else {
        int d = tid - DI;
        z_silu[(size_t)(pb+0)*DI + d] = silu(a0);
        z_silu[(size_t)(pb+1)*DI + d] = silu(a1);
        z_silu[(size_t)(pb+2)*DI + d] = silu(a2);
        z_silu[(size_t)(pb+3)*DI + d] = silu(a3);
    }
}

// ---------------- Stage 2: depthwise 3x3 conv + bias + silu ------------------
__global__ __launch_bounds__(256) void k_conv(const float* __restrict__ conv_in,
    const float* __restrict__ cw, const float* __restrict__ cb,
    float* __restrict__ xc)
{
    int idx = blockIdx.x*256 + threadIdx.x;        // over B*LL*DI (exact)
    int d = idx % DI;
    int p = (idx / DI) % LL;
    int b = idx / (DI*LL);
    int h = p / WW, w = p % WW;
    float acc = cb[d];
    #pragma unroll
    for (int dy = -1; dy <= 1; ++dy){
        int hy = h + dy; if (hy < 0 || hy >= HH) continue;
        #pragma unroll
        for (int dx = -1; dx <= 1; ++dx){
            int wx = w + dx; if (wx < 0 || wx >= WW) continue;
            acc = fmaf(conv_in[((size_t)b*LL + hy*WW + wx)*DI + d],
                       cw[d*9 + (dy+1)*3 + (dx+1)], acc);
        }
    }
    xc[idx] = silu(acc);
}

// ---------------- Stage 3: x_proj (38x192) + dt expand + softplus ------------
__global__ __launch_bounds__(256) void k_xproj(const float* __restrict__ xc,
   const float* __restrict__ xpw, const float* __restrict__ dtw,
   const float* __restrict__ dtb,
   float* __restrict__ delta, float* __restrict__ Bsb, float* __restrict__ Csb)
{
    __shared__ float su[CL][DI];
    __shared__ float sxd[CL][RK + 2*NS];   // 38 outputs per l
    int gb = blockIdx.x;
    int bk = gb / (LL/CL); int l0 = (gb % (LL/CL)) * CL;
    int b = bk >> 2, k = bk & 3;
    int tid = threadIdx.x;

    for (int e = tid; e < CL*DI; e += 256){
        int lo = e / DI, i = e % DI;
        su[lo][i] = xc[((size_t)b*LL + qmap(k, l0+lo))*DI + i];
    }
    __syncthreads();

    for (int oid = tid; oid < CL*(RK+2*NS); oid += 256){
        int lo = oid / (RK+2*NS), c = oid % (RK+2*NS);
        const float* wr = xpw + ((size_t)k*(RK+2*NS) + c)*DI;
        float acc = 0.f;
        #pragma unroll 4
        for (int i = 0; i < DI; ++i) acc = fmaf(su[lo][i], wr[i], acc);
        sxd[lo][c] = acc;
    }
    __syncthreads();

    for (int e = tid; e < CL*DI; e += 256){
        int lo = e / DI, d = e % DI;
        float a = dtb[k*DI + d];
        const float* wr = dtw + ((size_t)k*DI + d)*RK;
        #pragma unroll
        for (int r = 0; r < RK; ++r) a = fmaf(sxd[lo][r], wr[r], a);
        float sp = (a > 20.f) ? a : log1pf(__expf(a));   // softplus
        delta[((size_t)bk*LL + l0+lo)*DI + d] = sp;
    }
    if (tid < CL*NS){
        int lo = tid / NS, n = tid % NS;
        Bsb[((size_t)bk*LL + l0+lo)*NS + n] = sxd[lo][RK + n];
        Csb[((size_t)bk*LL + l0+lo)*NS + n] = sxd[lo][RK + NS + n];
    }
}

// ---------------- Stage 5: selective scan (sequential over L) ----------------
// block: 256 threads = 16 d-channels x 16 n-states; grid: (B*K) x (DI/16) = 192
__global__ __launch_bounds__(256) void k_scan(const float* __restrict__ delta,
    const float* __restrict__ xc, const float* __restrict__ Bsb, const float* __restrict__ Csb,
    const float* __restrict__ Alog, const float* __restrict__ Dsv,
    float* __restrict__ y_acc)
{
    __shared__ float sb[2][4][SCH][16];
    int gb = blockIdx.x;                 // 0..191
    int bk = gb / (DI/16), dt = gb % (DI/16);
    int b = bk >> 2, k = bk & 3;
    int tid = threadIdx.x;
    int n = tid & 15, dloc = tid >> 4;   // 0..15 each
    int d = dt*16 + dloc;

    float An = -__expf(Alog[((size_t)k*DI + d)*NS + n]);
    float Dv = Dsv[k*DI + d];

    const float* dbase = delta + (size_t)bk*LL*DI + dt*16;
    const float* xbase = xc    + (size_t)b*LL*DI  + dt*16;
    const float* Bbase = Bsb   + (size_t)bk*LL*NS;
    const float* Cbase = Csb   + (size_t)bk*LL*NS;
    float*       ybase = y_acc + (size_t)b*LL*DI  + dt*16;

    // each thread loads one element per array: (lo = dloc, i = n) -> coalesced
    auto load = [&](int c, int bi){
        int l = c*SCH + dloc;
        sb[bi][0][dloc][n] = dbase[(size_t)l*DI + n];
        sb[bi][1][dloc][n] = xbase[(size_t)qmap(k, l)*DI + n];
        sb[bi][2][dloc][n] = Bbase[(size_t)l*NS + n];
        sb[bi][3][dloc][n] = Cbase[(size_t)l*NS + n];
    };

    load(0, 0);
    __syncthreads();
    float h = 0.f;
    const int NCH = LL / SCH;            // 196 (exact)
    for (int c = 0; c < NCH; ++c){
        int bi = c & 1;
        if (c + 1 < NCH) load(c + 1, bi ^ 1);
        int l0 = c*SCH;
        #pragma unroll
        for (int lo = 0; lo < SCH; ++lo){
            float dl = sb[bi][0][lo][dloc];
            float uu = sb[bi][1][lo][dloc];
            float Bn = sb[bi][2][lo][n];
            float Cn = sb[bi][3][lo][n];
            float dA = __expf(dl * An);
            h = fmaf(dA, h, dl * uu * Bn);     // the only true serial dependency
            float yp = h * Cn;
            yp += __shfl_xor(yp, 1);
            yp += __shfl_xor(yp, 2);
            yp += __shfl_xor(yp, 4);
            yp += __shfl_xor(yp, 8);
            if (n == 0){
                // cross-merge: step l of direction k belongs to pixel qmap(k,l)
                atomicAdd(&ybase[(size_t)qmap(k, l0+lo)*DI + dloc], yp + uu * Dv);
            }
        }
        __syncthreads();
    }
}

// ---------------- Stage 6: LayerNorm + z-gate + out_proj ---------------------
__global__ __launch_bounds__(192) void k_lnout(const float* __restrict__ y_acc,
    const float* __restrict__ z_silu, const float* __restrict__ lnw,
    const float* __restrict__ lnb, const float* __restrict__ Wout,
    float* __restrict__ out)
{
    __shared__ float syz[DI];
    __shared__ float red[2][3];
    __shared__ float mb[2];
    int pg  = blockIdx.x;                 // b*LL + p
    int tid = threadIdx.x;                // d
    float v = y_acc[(size_t)pg*DI + tid];
    float s = v, sq = v*v;
    #pragma unroll
    for (int m = 32; m >= 1; m >>= 1){ s += __shfl_xor(s, m); sq += __shfl_xor(sq, m); }
    int wid = tid >> 6, lane = tid & 63;
    if (lane == 0){ red[0][wid] = s; red[1][wid] = sq; }
    __syncthreads();
    if (tid == 0){
        float ts = red[0][0] + red[0][1] + red[0][2];
        float tq = red[1][0] + red[1][1] + red[1][2];
        float mu  = ts * (1.f/DI);
        float var = tq * (1.f/DI) - mu*mu;
        mb[0] = mu; mb[1] = rsqrtf(var + 1e-5f);
    }
    __syncthreads();
    float yn = (v - mb[0]) * mb[1] * lnw[tid] + lnb[tid];
    syz[tid] = yn * z_silu[(size_t)pg*DI + tid];
    __syncthreads();
    if (tid < DM){
        const float* wr = Wout + (size_t)tid*DI;
        float acc = 0.f;
        #pragma unroll 4
        for (int i = 0; i < DI; ++i) acc = fmaf(syz[i], wr[i], acc);
        out[(size_t)pg*DM + tid] = acc;
    }
}

extern "C" void kernel_launch(void* const* d_in, const int* in_sizes, int n_in,
                              void* d_out, int out_size, void* d_ws, size_t ws_size,
                              hipStream_t stream)
{
    const float* x    = (const float*)d_in[0];
    const float* Win  = (const float*)d_in[1];
    const float* cw   = (const float*)d_in[2];
    const float* cb   = (const float*)d_in[3];
    const float* xpw  = (const float*)d_in[4];
    const float* dtw  = (const float*)d_in[5];
    const float* dtb  = (const float*)d_in[6];
    const float* Alog = (const float*)d_in[7];
    const float* Dsv  = (const float*)d_in[8];
    const float* lnw  = (const float*)d_in[9];
    const float* lnb  = (const float*)d_in[10];
    const float* Wout = (const float*)d_in[11];
    float* out = (float*)d_out;

    float* ws      = (float*)d_ws;
    float* conv_in = ws;                                    // [NPIX, DI]  (dead after k_conv)
    float* z_silu  = conv_in + (size_t)NPIX*DI;             // [NPIX, DI]
    float* xc      = z_silu  + (size_t)NPIX*DI;             // [NPIX, DI]
    float* delta   = xc      + (size_t)NPIX*DI;             // [B*K, LL, DI]
    float* Bsb     = delta   + (size_t)BB*KG*LL*DI;         // [B*K, LL, NS]
    float* Csb     = Bsb     + (size_t)BB*KG*LL*NS;         // [B*K, LL, NS]
    float* y_acc   = conv_in;                               // alias: conv_in dead by scan time

    hipLaunchKernelGGL(k_inproj, dim3(NPIX/4), dim3(384), 0, stream, x, Win, conv_in, z_silu);
    hipLaunchKernelGGL(k_conv,   dim3((NPIX*DI)/256), dim3(256), 0, stream, conv_in, cw, cb, xc);
    hipLaunchKernelGGL(k_xproj,  dim3(BB*KG*(LL/CL)), dim3(256), 0, stream, xc, xpw, dtw, dtb, delta, Bsb, Csb);
    hipMemsetAsync(y_acc, 0, (size_t)NPIX*DI*sizeof(float), stream);
    hipLaunchKernelGGL(k_scan,   dim3(BB*KG*(DI/16)), dim3(256), 0, stream, delta, xc, Bsb, Csb, Alog, Dsv, y_acc);
    hipLaunchKernelGGL(k_lnout,  dim3(NPIX), dim3(192), 0, stream, y_acc, z_silu, lnw, lnb, Wout, out);
}

// Round 3
// 818.220 us; speedup vs baseline: 1.5201x; 1.5201x over previous
//
#include <hip/hip_runtime.h>
#include <hip/hip_bf16.h>
#include <math.h>

#define BB 4
#define HH 56
#define WW 56
#define DM 96
#define DI 192
#define NS 16
#define RK 6
#define KG 4
#define LL (HH*WW)          // 3136
#define NPIX (BB*LL)        // 12544
#define CL 8                // xproj pixels per block
#define CHL 64              // scan chunk length
#define NCH (LL/CHL)        // 49 chunks
#define NDT (DI/16)         // 12 d-tiles

// pixel index (row-major) feeding/receiving scan position l of direction k
// k=0: identity, k=1: transpose(HW), k=2: flip(identity), k=3: flip(transpose)
static __device__ __forceinline__ int qmap(int k, int l){
    int m = (k & 2) ? (LL - 1 - l) : l;
    if (k & 1) { int w = m / HH; int h = m % HH; return h * WW + w; }
    return m;
}

static __device__ __forceinline__ float silu(float x){ return x / (1.f + __expf(-x)); }

// ---------------- Stage 1: in_proj (384x96 matvec per pixel), 4 px/block ----
__global__ __launch_bounds__(384) void k_inproj(const float* __restrict__ x,
        const float* __restrict__ Win,
        float* __restrict__ conv_in, float* __restrict__ z_silu)
{
    __shared__ float sx[4*DM];
    int pb  = blockIdx.x * 4;
    int tid = threadIdx.x;
    sx[tid] = x[(size_t)pb*DM + tid];
    __syncthreads();
    float a0=0.f, a1=0.f, a2=0.f, a3=0.f;
    const float* wr = Win + (size_t)tid*DM;
    #pragma unroll 4
    for (int i = 0; i < DM; ++i){
        float w = wr[i];
        a0 = fmaf(sx[i],        w, a0);
        a1 = fmaf(sx[DM+i],     w, a1);
        a2 = fmaf(sx[2*DM+i],   w, a2);
        a3 = fmaf(sx[3*DM+i],   w, a3);
    }
    if (tid < DI){
        conv_in[(size_t)(pb+0)*DI + tid] = a0;
        conv_in[(size_t)(pb+1)*DI + tid] = a1;
        conv_in[(size_t)(pb+2)*DI + tid] = a2;
        conv_in[(size_t)(pb+3)*DI + tid] = a3;
    } else {
        int d = tid - DI;
        z_silu[(size_t)(pb+0)*DI + d] = silu(a0);
        z_silu[(size_t)(pb+1)*DI + d] = silu(a1);
        z_silu[(size_t)(pb+2)*DI + d] = silu(a2);
        z_silu[(size_t)(pb+3)*DI + d] = silu(a3);
    }
}

// ---------------- Stage 2: depthwise 3x3 conv + bias + silu ------------------
__global__ __launch_bounds__(256) void k_conv(const float* __restrict__ conv_in,
    const float* __restrict__ cw, const float* __restrict__ cb,
    float* __restrict__ xc)
{
    int idx = blockIdx.x*256 + threadIdx.x;
    int d = idx % DI;
    int p = (idx / DI) % LL;
    int b = idx / (DI*LL);
    int h = p / WW, w = p % WW;
    float acc = cb[d];
    #pragma unroll
    for (int dy = -1; dy <= 1; ++dy){
        int hy = h + dy; if (hy < 0 || hy >= HH) continue;
        #pragma unroll
        for (int dx = -1; dx <= 1; ++dx){
            int wx = w + dx; if (wx < 0 || wx >= WW) continue;
            acc = fmaf(conv_in[((size_t)b*LL + hy*WW + wx)*DI + d],
                       cw[d*9 + (dy+1)*3 + (dx+1)], acc);
        }
    }
    xc[idx] = silu(acc);
}

// ---------------- Stage 3: x_proj (38x192) + dt expand + softplus ------------
__global__ __launch_bounds__(256) void k_xproj(const float* __restrict__ xc,
   const float* __restrict__ xpw, const float* __restrict__ dtw,
   const float* __restrict__ dtb,
   float* __restrict__ delta, float* __restrict__ Bsb, float* __restrict__ Csb)
{
    __shared__ float su[CL][DI];
    __shared__ float sxd[CL][RK + 2*NS];
    int gb = blockIdx.x;
    int bk = gb / (LL/CL); int l0 = (gb % (LL/CL)) * CL;
    int b = bk >> 2, k = bk & 3;
    int tid = threadIdx.x;

    for (int e = tid; e < CL*DI; e += 256){
        int lo = e / DI, i = e % DI;
        su[lo][i] = xc[((size_t)b*LL + qmap(k, l0+lo))*DI + i];
    }
    __syncthreads();

    for (int oid = tid; oid < CL*(RK+2*NS); oid += 256){
        int lo = oid / (RK+2*NS), c = oid % (RK+2*NS);
        const float* wr = xpw + ((size_t)k*(RK+2*NS) + c)*DI;
        float acc = 0.f;
        #pragma unroll 4
        for (int i = 0; i < DI; ++i) acc = fmaf(su[lo][i], wr[i], acc);
        sxd[lo][c] = acc;
    }
    __syncthreads();

    for (int e = tid; e < CL*DI; e += 256){
        int lo = e / DI, d = e % DI;
        float a = dtb[k*DI + d];
        const float* wr = dtw + ((size_t)k*DI + d)*RK;
        #pragma unroll
        for (int r = 0; r < RK; ++r) a = fmaf(sxd[lo][r], wr[r], a);
        float sp = (a > 20.f) ? a : log1pf(__expf(a));
        delta[((size_t)bk*LL + l0+lo)*DI + d] = sp;
    }
    if (tid < CL*NS){
        int lo = tid / NS, n = tid % NS;
        Bsb[((size_t)bk*LL + l0+lo)*NS + n] = sxd[lo][RK + n];
        Csb[((size_t)bk*LL + l0+lo)*NS + n] = sxd[lo][RK + NS + n];
    }
}

// ---------------- Stage 5a: per-chunk local scan (serial chain = 64) ---------
// grid: bk(16) x dt(12) x ch(49); block 256 = 16 d x 16 n
__global__ __launch_bounds__(256) void k_scan_local(const float* __restrict__ delta,
    const float* __restrict__ xc, const float* __restrict__ Bsb, const float* __restrict__ Csb,
    const float* __restrict__ Alog, const float* __restrict__ Dsv,
    float* __restrict__ y_acc, float* __restrict__ hend, float* __restrict__ sumdl)
{
    __shared__ float sdl[CHL][16], su[CHL][16], sB[CHL][16], sC[CHL][16];
    int bid = blockIdx.x;
    int bk = bid / (NDT*NCH); int rem = bid % (NDT*NCH);
    int dt = rem / NCH, ch = rem % NCH;
    int blk = bk*NDT + dt;
    int b = bk >> 2, k = bk & 3;
    int tid = threadIdx.x;
    int n = tid & 15, dloc = tid >> 4;
    int d = dt*16 + dloc;
    int l0 = ch*CHL;

    const float* dbase = delta + (size_t)bk*LL*DI + dt*16;
    const float* xbase = xc    + (size_t)b*LL*DI  + dt*16;
    const float* Bbase = Bsb   + ((size_t)bk*LL + l0)*NS;
    const float* Cbase = Csb   + ((size_t)bk*LL + l0)*NS;
    float*       ybase = y_acc + (size_t)b*LL*DI  + dt*16;

    for (int e = tid; e < CHL*16; e += 256){
        int lo = e >> 4, i = e & 15;
        sdl[lo][i] = dbase[(size_t)(l0+lo)*DI + i];
        su [lo][i] = xbase[(size_t)qmap(k, l0+lo)*DI + i];
        ((float*)sB)[e] = Bbase[e];
        ((float*)sC)[e] = Cbase[e];
    }
    __syncthreads();

    float An = -__expf(Alog[((size_t)k*DI + d)*NS + n]);
    float Dv = Dsv[k*DI + d];

    float h = 0.f;
    #pragma unroll 4
    for (int lo = 0; lo < CHL; ++lo){
        float dl = sdl[lo][dloc];
        float uu = su [lo][dloc];
        float Bn = sB [lo][n];
        float Cn = sC [lo][n];
        h = fmaf(__expf(dl * An), h, dl * uu * Bn);
        float yp = h * Cn;
        yp += __shfl_xor(yp, 1);
        yp += __shfl_xor(yp, 2);
        yp += __shfl_xor(yp, 4);
        yp += __shfl_xor(yp, 8);
        if (n == 0)
            atomicAdd(&ybase[(size_t)qmap(k, l0+lo)*DI + dloc], yp + uu * Dv);
    }
    hend[((size_t)blk*NCH + ch)*256 + tid] = h;

    // sum of dl over the chunk, per d: each n-lane sums 4 rows, shfl-reduce
    float ps = sdl[n*4+0][dloc] + sdl[n*4+1][dloc] + sdl[n*4+2][dloc] + sdl[n*4+3][dloc];
    ps += __shfl_xor(ps, 1);
    ps += __shfl_xor(ps, 2);
    ps += __shfl_xor(ps, 4);
    ps += __shfl_xor(ps, 8);
    if (n == 0) sumdl[((size_t)blk*NCH + ch)*16 + dloc] = ps;
}

// ---------------- Stage 5b: combine chunk states (serial = 49) ---------------
// grid: 192 blocks (bk*12+dt); block 256 = 16 d x 16 n
__global__ __launch_bounds__(256) void k_scan_comb(const float* __restrict__ hend,
    const float* __restrict__ sumdl, const float* __restrict__ Alog,
    float* __restrict__ H0buf)
{
    int blk = blockIdx.x;
    int bk = blk / NDT, dt = blk % NDT;
    int k = bk & 3;
    int tid = threadIdx.x;
    int n = tid & 15, dloc = tid >> 4;
    int d = dt*16 + dloc;
    float An = -__expf(Alog[((size_t)k*DI + d)*NS + n]);
    float H = 0.f;
    for (int c = 0; c < NCH; ++c){
        H0buf[((size_t)blk*NCH + c)*256 + tid] = H;
        float he = hend [((size_t)blk*NCH + c)*256 + tid];
        float S  = sumdl[((size_t)blk*NCH + c)*16 + dloc];
        H = fmaf(__expf(An * S), H, he);
    }
}

// ---------------- Stage 5c: apply carried-state correction (no serial chain) -
// grid: 192 x 48 (ch=1..48; ch=0 has H0=0); block 256 = 16 d x 16 n
__global__ __launch_bounds__(256) void k_scan_fix(const float* __restrict__ delta,
    const float* __restrict__ Csb, const float* __restrict__ H0buf,
    const float* __restrict__ Alog, float* __restrict__ y_acc)
{
    __shared__ float scum[CHL][16], sC[CHL][16];
    int bid = blockIdx.x;
    int blk = bid / (NCH-1);
    int ch  = bid % (NCH-1) + 1;
    int bk = blk / NDT, dt = blk % NDT;
    int b = bk >> 2, k = bk & 3;
    int tid = threadIdx.x;
    int n = tid & 15, dloc = tid >> 4;
    int d = dt*16 + dloc;
    int l0 = ch*CHL;

    const float* dbase = delta + (size_t)bk*LL*DI + dt*16;
    const float* Cbase = Csb   + ((size_t)bk*LL + l0)*NS;
    float*       ybase = y_acc + (size_t)b*LL*DI  + dt*16;

    for (int e = tid; e < CHL*16; e += 256){
        int lo = e >> 4, i = e & 15;
        scum[lo][i] = dbase[(size_t)(l0+lo)*DI + i];   // holds dl for now
        ((float*)sC)[e] = Cbase[e];
    }
    __syncthreads();

    // inclusive cumsum of dl over the 64 chunk steps, per d.
    // lane n handles steps [n*4, n*4+4); prefix across the 16 n-lanes.
    float v0 = scum[n*4+0][dloc];
    float v1 = scum[n*4+1][dloc];
    float v2 = scum[n*4+2][dloc];
    float v3 = scum[n*4+3][dloc];
    float c1 = v0, c2 = c1+v1, c3 = c2+v2, c4 = c3+v3;
    float inc = c4;
    #pragma unroll
    for (int s = 1; s < 16; s <<= 1){
        float t = __shfl_up(inc, s, 16);
        if ((tid & 15) >= s) inc += t;
    }
    float excl = inc - c4;
    __syncthreads();
    scum[n*4+0][dloc] = excl + c1;
    scum[n*4+1][dloc] = excl + c2;
    scum[n*4+2][dloc] = excl + c3;
    scum[n*4+3][dloc] = excl + c4;
    __syncthreads();

    float An = -__expf(Alog[((size_t)k*DI + d)*NS + n]);
    float H  = H0buf[((size_t)blk*NCH + ch)*256 + tid];

    #pragma unroll 4
    for (int lo = 0; lo < CHL; ++lo){
        float yp = __expf(An * scum[lo][dloc]) * H * sC[lo][n];
        yp += __shfl_xor(yp, 1);
        yp += __shfl_xor(yp, 2);
        yp += __shfl_xor(yp, 4);
        yp += __shfl_xor(yp, 8);
        if (n == 0)
            atomicAdd(&ybase[(size_t)qmap(k, l0+lo)*DI + dloc], yp);
    }
}

// ---------------- Stage 6: LayerNorm + z-gate + out_proj ---------------------
__global__ __launch_bounds__(192) void k_lnout(const float* __restrict__ y_acc,
    const float* __restrict__ z_silu, const float* __restrict__ lnw,
    const float* __restrict__ lnb, const float* __restrict__ Wout,
    float* __restrict__ out)
{
    __shared__ float syz[DI];
    __shared__ float red[2][3];
    __shared__ float mb[2];
    int pg  = blockIdx.x;
    int tid = threadIdx.x;
    float v = y_acc[(size_t)pg*DI + tid];
    float s = v, sq = v*v;
    #pragma unroll
    for (int m = 32; m >= 1; m >>= 1){ s += __shfl_xor(s, m); sq += __shfl_xor(sq, m); }
    int wid = tid >> 6, lane = tid & 63;
    if (lane == 0){ red[0][wid] = s; red[1][wid] = sq; }
    __syncthreads();
    if (tid == 0){
        float ts = red[0][0] + red[0][1] + red[0][2];
        float tq = red[1][0] + red[1][1] + red[1][2];
        float mu  = ts * (1.f/DI);
        float var = tq * (1.f/DI) - mu*mu;
        mb[0] = mu; mb[1] = rsqrtf(var + 1e-5f);
    }
    __syncthreads();
    float yn = (v - mb[0]) * mb[1] * lnw[tid] + lnb[tid];
    syz[tid] = yn * z_silu[(size_t)pg*DI + tid];
    __syncthreads();
    if (tid < DM){
        const float* wr = Wout + (size_t)tid*DI;
        float acc = 0.f;
        #pragma unroll 4
        for (int i = 0; i < DI; ++i) acc = fmaf(syz[i], wr[i], acc);
        out[(size_t)pg*DM + tid] = acc;
    }
}

extern "C" void kernel_launch(void* const* d_in, const int* in_sizes, int n_in,
                              void* d_out, int out_size, void* d_ws, size_t ws_size,
                              hipStream_t stream)
{
    const float* x    = (const float*)d_in[0];
    const float* Win  = (const float*)d_in[1];
    const float* cw   = (const float*)d_in[2];
    const float* cb   = (const float*)d_in[3];
    const float* xpw  = (const float*)d_in[4];
    const float* dtw  = (const float*)d_in[5];
    const float* dtb  = (const float*)d_in[6];
    const float* Alog = (const float*)d_in[7];
    const float* Dsv  = (const float*)d_in[8];
    const float* lnw  = (const float*)d_in[9];
    const float* lnb  = (const float*)d_in[10];
    const float* Wout = (const float*)d_in[11];
    float* out = (float*)d_out;

    float* ws      = (float*)d_ws;
    float* conv_in = ws;                                    // [NPIX,DI] dead after k_conv
    float* z_silu  = conv_in + (size_t)NPIX*DI;             // [NPIX,DI]
    float* xc      = z_silu  + (size_t)NPIX*DI;             // [NPIX,DI] dead after k_scan_local
    float* delta   = xc      + (size_t)NPIX*DI;             // [16,LL,DI]
    float* Bsb     = delta   + (size_t)BB*KG*LL*DI;         // [16,LL,NS]
    float* Csb     = Bsb     + (size_t)BB*KG*LL*NS;         // [16,LL,NS]
    float* sumdl   = Csb     + (size_t)BB*KG*LL*NS;         // [192,49,16]
    float* y_acc   = sumdl   + (size_t)192*NCH*16;          // [NPIX,DI]
    float* hend    = conv_in;                               // alias: [192,49,256]
    float* H0buf   = xc;                                    // alias: [192,49,256]

    hipLaunchKernelGGL(k_inproj, dim3(NPIX/4), dim3(384), 0, stream, x, Win, conv_in, z_silu);
    hipLaunchKernelGGL(k_conv,   dim3((NPIX*DI)/256), dim3(256), 0, stream, conv_in, cw, cb, xc);
    hipLaunchKernelGGL(k_xproj,  dim3(BB*KG*(LL/CL)), dim3(256), 0, stream, xc, xpw, dtw, dtb, delta, Bsb, Csb);
    hipMemsetAsync(y_acc, 0, (size_t)NPIX*DI*sizeof(float), stream);
    hipLaunchKernelGGL(k_scan_local, dim3(BB*KG*NDT*NCH), dim3(256), 0, stream,
                       delta, xc, Bsb, Csb, Alog, Dsv, y_acc, hend, sumdl);
    hipLaunchKernelGGL(k_scan_comb,  dim3(BB*KG*NDT), dim3(256), 0, stream,
                       hend, sumdl, Alog, H0buf);
    hipLaunchKernelGGL(k_scan_fix,   dim3(BB*KG*NDT*(NCH-1)), dim3(256), 0, stream,
                       delta, Csb, H0buf, Alog, y_acc);
    hipLaunchKernelGGL(k_lnout,  dim3(NPIX), dim3(192), 0, stream, y_acc, z_silu, lnw, lnb, Wout, out);
}

// Round 4
// 710.694 us; speedup vs baseline: 1.7501x; 1.1513x over previous
//
#include <hip/hip_runtime.h>
#include <hip/hip_bf16.h>
#include <math.h>

#define BB 4
#define HH 56
#define WW 56
#define DM 96
#define DI 192
#define NS 16
#define RK 6
#define KG 4
#define LL (HH*WW)          // 3136
#define NPIX (BB*LL)        // 12544
#define CHL 64              // scan chunk length
#define NCH (LL/CHL)        // 49 chunks
#define NDT (DI/16)         // 12 d-tiles
#define XP 32               // xproj pixels per block
#define NC 38               // RK + 2*NS
#define PAD 196             // padded row length (16B-aligned, bank-spread)

// pixel index (row-major) feeding/receiving scan position l of direction k
// k=0: identity, k=1: transpose(HW), k=2: flip(identity), k=3: flip(transpose)
static __device__ __forceinline__ int qmap(int k, int l){
    int m = (k & 2) ? (LL - 1 - l) : l;
    if (k & 1) { int w = m / HH; int h = m % HH; return h * WW + w; }
    return m;
}

static __device__ __forceinline__ float silu(float x){ return x / (1.f + __expf(-x)); }

// ---------------- Stage 1: in_proj (384x96 matvec per pixel), 4 px/block ----
__global__ __launch_bounds__(384) void k_inproj(const float* __restrict__ x,
        const float* __restrict__ Win,
        float* __restrict__ conv_in, float* __restrict__ z_silu)
{
    __shared__ float sx[4*DM];
    int pb  = blockIdx.x * 4;
    int tid = threadIdx.x;
    sx[tid] = x[(size_t)pb*DM + tid];
    __syncthreads();
    float a0=0.f, a1=0.f, a2=0.f, a3=0.f;
    const float* wr = Win + (size_t)tid*DM;
    #pragma unroll 4
    for (int i = 0; i < DM; ++i){
        float w = wr[i];
        a0 = fmaf(sx[i],        w, a0);
        a1 = fmaf(sx[DM+i],     w, a1);
        a2 = fmaf(sx[2*DM+i],   w, a2);
        a3 = fmaf(sx[3*DM+i],   w, a3);
    }
    if (tid < DI){
        conv_in[(size_t)(pb+0)*DI + tid] = a0;
        conv_in[(size_t)(pb+1)*DI + tid] = a1;
        conv_in[(size_t)(pb+2)*DI + tid] = a2;
        conv_in[(size_t)(pb+3)*DI + tid] = a3;
    } else {
        int d = tid - DI;
        z_silu[(size_t)(pb+0)*DI + d] = silu(a0);
        z_silu[(size_t)(pb+1)*DI + d] = silu(a1);
        z_silu[(size_t)(pb+2)*DI + d] = silu(a2);
        z_silu[(size_t)(pb+3)*DI + d] = silu(a3);
    }
}

// ---------------- Stage 2: depthwise 3x3 conv + bias + silu ------------------
__global__ __launch_bounds__(256) void k_conv(const float* __restrict__ conv_in,
    const float* __restrict__ cw, const float* __restrict__ cb,
    float* __restrict__ xc)
{
    int idx = blockIdx.x*256 + threadIdx.x;
    int d = idx % DI;
    int p = (idx / DI) % LL;
    int b = idx / (DI*LL);
    int h = p / WW, w = p % WW;
    float acc = cb[d];
    #pragma unroll
    for (int dy = -1; dy <= 1; ++dy){
        int hy = h + dy; if (hy < 0 || hy >= HH) continue;
        #pragma unroll
        for (int dx = -1; dx <= 1; ++dx){
            int wx = w + dx; if (wx < 0 || wx >= WW) continue;
            acc = fmaf(conv_in[((size_t)b*LL + hy*WW + wx)*DI + d],
                       cw[d*9 + (dy+1)*3 + (dx+1)], acc);
        }
    }
    xc[idx] = silu(acc);
}

// ---------------- Stage 3: x_proj as LDS-tiled GEMM (M=32,N=38,K=192) --------
// grid: bk(16) x (LL/32); block 256. Weights+pixels in padded LDS, 2x2 reg tile.
__global__ __launch_bounds__(256) void k_xproj(const float* __restrict__ xc,
   const float* __restrict__ xpw, const float* __restrict__ dtw,
   const float* __restrict__ dtb,
   float* __restrict__ delta, float* __restrict__ Bsb, float* __restrict__ Csb)
{
    __shared__ float sw[NC*PAD];        // 38 x 196
    __shared__ float su[XP*PAD];        // 32 x 196
    __shared__ float sxd[XP][40];       // 32 x 38 (padded)
    __shared__ float sdtw[DI*RK];       // 192 x 6
    int gb = blockIdx.x;
    int bk = gb / (LL/XP); int l0 = (gb % (LL/XP)) * XP;
    int b = bk >> 2, k = bk & 3;
    int tid = threadIdx.x;

    // stage weights (38 rows x 48 float4)
    for (int t = tid; t < NC*48; t += 256){
        int c = t / 48, i4 = t % 48;
        float4 w = ((const float4*)(xpw + ((size_t)k*NC + c)*DI))[i4];
        *((float4*)&sw[c*PAD + i4*4]) = w;
    }
    // stage 32 pixel rows
    for (int t = tid; t < XP*48; t += 256){
        int lo = t / 48, i4 = t % 48;
        int p = qmap(k, l0 + lo);
        float4 u = ((const float4*)(xc + ((size_t)b*LL + p)*DI))[i4];
        *((float4*)&su[lo*PAD + i4*4]) = u;
    }
    // stage dt weights
    for (int t = tid; t < DI*RK; t += 256) sdtw[t] = dtw[(size_t)k*DI*RK + t];
    __syncthreads();

    // 2x2 register-blocked tile: quad q -> (c0,c1) x (lo, lo+16)
    for (int q = tid; q < 19*16; q += 256){
        int c2 = q >> 4, lo = q & 15;
        int c0 = 2*c2, c1 = c0 + 1;
        const float4* wa = (const float4*)&sw[c0*PAD];
        const float4* wb = (const float4*)&sw[c1*PAD];
        const float4* ua = (const float4*)&su[lo*PAD];
        const float4* ub = (const float4*)&su[(lo+16)*PAD];
        float a00=0.f, a01=0.f, a10=0.f, a11=0.f;
        #pragma unroll 4
        for (int i4 = 0; i4 < 48; ++i4){
            float4 w0 = wa[i4], w1 = wb[i4], u0 = ua[i4], u1 = ub[i4];
            a00 = fmaf(u0.x,w0.x,a00); a00 = fmaf(u0.y,w0.y,a00);
            a00 = fmaf(u0.z,w0.z,a00); a00 = fmaf(u0.w,w0.w,a00);
            a01 = fmaf(u0.x,w1.x,a01); a01 = fmaf(u0.y,w1.y,a01);
            a01 = fmaf(u0.z,w1.z,a01); a01 = fmaf(u0.w,w1.w,a01);
            a10 = fmaf(u1.x,w0.x,a10); a10 = fmaf(u1.y,w0.y,a10);
            a10 = fmaf(u1.z,w0.z,a10); a10 = fmaf(u1.w,w0.w,a10);
            a11 = fmaf(u1.x,w1.x,a11); a11 = fmaf(u1.y,w1.y,a11);
            a11 = fmaf(u1.z,w1.z,a11); a11 = fmaf(u1.w,w1.w,a11);
        }
        sxd[lo][c0] = a00; sxd[lo][c1] = a01;
        sxd[lo+16][c0] = a10; sxd[lo+16][c1] = a11;
    }
    __syncthreads();

    // dt expansion + softplus + delta/B/C writes (coalesced rows)
    for (int e = tid; e < XP*DI; e += 256){
        int lo = e / DI, d = e % DI;
        float a = dtb[k*DI + d];
        #pragma unroll
        for (int r = 0; r < RK; ++r) a = fmaf(sxd[lo][r], sdtw[d*RK + r], a);
        float sp = (a > 20.f) ? a : log1pf(__expf(a));
        delta[((size_t)bk*LL + l0+lo)*DI + d] = sp;
    }
    for (int t = tid; t < XP*NS; t += 256){
        int lo = t / NS, n = t % NS;
        Bsb[((size_t)bk*LL + l0+lo)*NS + n] = sxd[lo][RK + n];
        Csb[((size_t)bk*LL + l0+lo)*NS + n] = sxd[lo][RK + NS + n];
    }
}

// ---------------- Stage 5a: per-chunk local scan (serial chain = 64) ---------
// grid: bk(16) x dt(12) x ch(49); block 256 = 16 d x 16 n
__global__ __launch_bounds__(256) void k_scan_local(const float* __restrict__ delta,
    const float* __restrict__ xc, const float* __restrict__ Bsb, const float* __restrict__ Csb,
    const float* __restrict__ Alog, const float* __restrict__ Dsv,
    float* __restrict__ y_acc, float* __restrict__ hend, float* __restrict__ sumdl)
{
    __shared__ float sdl[CHL][16], su[CHL][16], sB[CHL][16], sC[CHL][16];
    int bid = blockIdx.x;
    int bk = bid / (NDT*NCH); int rem = bid % (NDT*NCH);
    int dt = rem / NCH, ch = rem % NCH;
    int blk = bk*NDT + dt;
    int b = bk >> 2, k = bk & 3;
    int tid = threadIdx.x;
    int n = tid & 15, dloc = tid >> 4;
    int d = dt*16 + dloc;
    int l0 = ch*CHL;

    const float* dbase = delta + (size_t)bk*LL*DI + dt*16;
    const float* xbase = xc    + (size_t)b*LL*DI  + dt*16;
    const float* Bbase = Bsb   + ((size_t)bk*LL + l0)*NS;
    const float* Cbase = Csb   + ((size_t)bk*LL + l0)*NS;
    float*       ybase = y_acc + (size_t)b*LL*DI  + dt*16;

    for (int e = tid; e < CHL*16; e += 256){
        int lo = e >> 4, i = e & 15;
        sdl[lo][i] = dbase[(size_t)(l0+lo)*DI + i];
        su [lo][i] = xbase[(size_t)qmap(k, l0+lo)*DI + i];
        ((float*)sB)[e] = Bbase[e];
        ((float*)sC)[e] = Cbase[e];
    }
    __syncthreads();

    float An = -__expf(Alog[((size_t)k*DI + d)*NS + n]);
    float Dv = Dsv[k*DI + d];

    float h = 0.f;
    #pragma unroll 4
    for (int lo = 0; lo < CHL; ++lo){
        float dl = sdl[lo][dloc];
        float uu = su [lo][dloc];
        float Bn = sB [lo][n];
        float Cn = sC [lo][n];
        h = fmaf(__expf(dl * An), h, dl * uu * Bn);
        float yp = h * Cn;
        yp += __shfl_xor(yp, 1);
        yp += __shfl_xor(yp, 2);
        yp += __shfl_xor(yp, 4);
        yp += __shfl_xor(yp, 8);
        if (n == 0)
            atomicAdd(&ybase[(size_t)qmap(k, l0+lo)*DI + dloc], yp + uu * Dv);
    }
    hend[((size_t)blk*NCH + ch)*256 + tid] = h;

    float ps = sdl[n*4+0][dloc] + sdl[n*4+1][dloc] + sdl[n*4+2][dloc] + sdl[n*4+3][dloc];
    ps += __shfl_xor(ps, 1);
    ps += __shfl_xor(ps, 2);
    ps += __shfl_xor(ps, 4);
    ps += __shfl_xor(ps, 8);
    if (n == 0) sumdl[((size_t)blk*NCH + ch)*16 + dloc] = ps;
}

// ---------------- Stage 5b: combine chunk states (serial = 49) ---------------
__global__ __launch_bounds__(256) void k_scan_comb(const float* __restrict__ hend,
    const float* __restrict__ sumdl, const float* __restrict__ Alog,
    float* __restrict__ H0buf)
{
    int blk = blockIdx.x;
    int bk = blk / NDT, dt = blk % NDT;
    int k = bk & 3;
    int tid = threadIdx.x;
    int n = tid & 15, dloc = tid >> 4;
    int d = dt*16 + dloc;
    float An = -__expf(Alog[((size_t)k*DI + d)*NS + n]);
    float H = 0.f;
    for (int c = 0; c < NCH; ++c){
        H0buf[((size_t)blk*NCH + c)*256 + tid] = H;
        float he = hend [((size_t)blk*NCH + c)*256 + tid];
        float S  = sumdl[((size_t)blk*NCH + c)*16 + dloc];
        H = fmaf(__expf(An * S), H, he);
    }
}

// ---------------- Stage 5c: apply carried-state correction -------------------
__global__ __launch_bounds__(256) void k_scan_fix(const float* __restrict__ delta,
    const float* __restrict__ Csb, const float* __restrict__ H0buf,
    const float* __restrict__ Alog, float* __restrict__ y_acc)
{
    __shared__ float scum[CHL][16], sC[CHL][16];
    int bid = blockIdx.x;
    int blk = bid / (NCH-1);
    int ch  = bid % (NCH-1) + 1;
    int bk = blk / NDT, dt = blk % NDT;
    int b = bk >> 2, k = bk & 3;
    int tid = threadIdx.x;
    int n = tid & 15, dloc = tid >> 4;
    int d = dt*16 + dloc;
    int l0 = ch*CHL;

    const float* dbase = delta + (size_t)bk*LL*DI + dt*16;
    const float* Cbase = Csb   + ((size_t)bk*LL + l0)*NS;
    float*       ybase = y_acc + (size_t)b*LL*DI  + dt*16;

    for (int e = tid; e < CHL*16; e += 256){
        int lo = e >> 4, i = e & 15;
        scum[lo][i] = dbase[(size_t)(l0+lo)*DI + i];
        ((float*)sC)[e] = Cbase[e];
    }
    __syncthreads();

    float v0 = scum[n*4+0][dloc];
    float v1 = scum[n*4+1][dloc];
    float v2 = scum[n*4+2][dloc];
    float v3 = scum[n*4+3][dloc];
    float c1 = v0, c2 = c1+v1, c3 = c2+v2, c4 = c3+v3;
    float inc = c4;
    #pragma unroll
    for (int s = 1; s < 16; s <<= 1){
        float t = __shfl_up(inc, s, 16);
        if ((tid & 15) >= s) inc += t;
    }
    float excl = inc - c4;
    __syncthreads();
    scum[n*4+0][dloc] = excl + c1;
    scum[n*4+1][dloc] = excl + c2;
    scum[n*4+2][dloc] = excl + c3;
    scum[n*4+3][dloc] = excl + c4;
    __syncthreads();

    float An = -__expf(Alog[((size_t)k*DI + d)*NS + n]);
    float H  = H0buf[((size_t)blk*NCH + ch)*256 + tid];

    #pragma unroll 4
    for (int lo = 0; lo < CHL; ++lo){
        float yp = __expf(An * scum[lo][dloc]) * H * sC[lo][n];
        yp += __shfl_xor(yp, 1);
        yp += __shfl_xor(yp, 2);
        yp += __shfl_xor(yp, 4);
        yp += __shfl_xor(yp, 8);
        if (n == 0)
            atomicAdd(&ybase[(size_t)qmap(k, l0+lo)*DI + dloc], yp);
    }
}

// ---------------- Stage 6: LayerNorm + z-gate + out_proj ---------------------
__global__ __launch_bounds__(192) void k_lnout(const float* __restrict__ y_acc,
    const float* __restrict__ z_silu, const float* __restrict__ lnw,
    const float* __restrict__ lnb, const float* __restrict__ Wout,
    float* __restrict__ out)
{
    __shared__ float syz[DI];
    __shared__ float red[2][3];
    __shared__ float mb[2];
    int pg  = blockIdx.x;
    int tid = threadIdx.x;
    float v = y_acc[(size_t)pg*DI + tid];
    float s = v, sq = v*v;
    #pragma unroll
    for (int m = 32; m >= 1; m >>= 1){ s += __shfl_xor(s, m); sq += __shfl_xor(sq, m); }
    int wid = tid >> 6, lane = tid & 63;
    if (lane == 0){ red[0][wid] = s; red[1][wid] = sq; }
    __syncthreads();
    if (tid == 0){
        float ts = red[0][0] + red[0][1] + red[0][2];
        float tq = red[1][0] + red[1][1] + red[1][2];
        float mu  = ts * (1.f/DI);
        float var = tq * (1.f/DI) - mu*mu;
        mb[0] = mu; mb[1] = rsqrtf(var + 1e-5f);
    }
    __syncthreads();
    float yn = (v - mb[0]) * mb[1] * lnw[tid] + lnb[tid];
    syz[tid] = yn * z_silu[(size_t)pg*DI + tid];
    __syncthreads();
    if (tid < DM){
        const float* wr = Wout + (size_t)tid*DI;
        float acc = 0.f;
        #pragma unroll 4
        for (int i = 0; i < DI; ++i) acc = fmaf(syz[i], wr[i], acc);
        out[(size_t)pg*DM + tid] = acc;
    }
}

extern "C" void kernel_launch(void* const* d_in, const int* in_sizes, int n_in,
                              void* d_out, int out_size, void* d_ws, size_t ws_size,
                              hipStream_t stream)
{
    const float* x    = (const float*)d_in[0];
    const float* Win  = (const float*)d_in[1];
    const float* cw   = (const float*)d_in[2];
    const float* cb   = (const float*)d_in[3];
    const float* xpw  = (const float*)d_in[4];
    const float* dtw  = (const float*)d_in[5];
    const float* dtb  = (const float*)d_in[6];
    const float* Alog = (const float*)d_in[7];
    const float* Dsv  = (const float*)d_in[8];
    const float* lnw  = (const float*)d_in[9];
    const float* lnb  = (const float*)d_in[10];
    const float* Wout = (const float*)d_in[11];
    float* out = (float*)d_out;

    float* ws      = (float*)d_ws;
    float* conv_in = ws;                                    // [NPIX,DI] dead after k_conv
    float* z_silu  = conv_in + (size_t)NPIX*DI;             // [NPIX,DI]
    float* xc      = z_silu  + (size_t)NPIX*DI;             // [NPIX,DI] dead after k_scan_local
    float* delta   = xc      + (size_t)NPIX*DI;             // [16,LL,DI]
    float* Bsb     = delta   + (size_t)BB*KG*LL*DI;         // [16,LL,NS]
    float* Csb     = Bsb     + (size_t)BB*KG*LL*NS;         // [16,LL,NS]
    float* sumdl   = Csb     + (size_t)BB*KG*LL*NS;         // [192,49,16]
    float* y_acc   = sumdl   + (size_t)192*NCH*16;          // [NPIX,DI]
    float* hend    = conv_in;                               // alias: [192,49,256]
    float* H0buf   = xc;                                    // alias: [192,49,256]

    hipLaunchKernelGGL(k_inproj, dim3(NPIX/4), dim3(384), 0, stream, x, Win, conv_in, z_silu);
    hipLaunchKernelGGL(k_conv,   dim3((NPIX*DI)/256), dim3(256), 0, stream, conv_in, cw, cb, xc);
    hipLaunchKernelGGL(k_xproj,  dim3(BB*KG*(LL/XP)), dim3(256), 0, stream, xc, xpw, dtw, dtb, delta, Bsb, Csb);
    hipMemsetAsync(y_acc, 0, (size_t)NPIX*DI*sizeof(float), stream);
    hipLaunchKernelGGL(k_scan_local, dim3(BB*KG*NDT*NCH), dim3(256), 0, stream,
                       delta, xc, Bsb, Csb, Alog, Dsv, y_acc, hend, sumdl);
    hipLaunchKernelGGL(k_scan_comb,  dim3(BB*KG*NDT), dim3(256), 0, stream,
                       hend, sumdl, Alog, H0buf);
    hipLaunchKernelGGL(k_scan_fix,   dim3(BB*KG*NDT*(NCH-1)), dim3(256), 0, stream,
                       delta, Csb, H0buf, Alog, y_acc);
    hipLaunchKernelGGL(k_lnout,  dim3(NPIX), dim3(192), 0, stream, y_acc, z_silu, lnw, lnb, Wout, out);
}